// Round 6
// baseline (372.068 us; speedup 1.0000x reference)
//
#include <hip/hip_runtime.h>
#include <stdint.h>

typedef __attribute__((ext_vector_type(8))) short short8;
typedef __attribute__((ext_vector_type(4))) float f32x4;

static constexpr int D  = 1024;
static constexpr int H  = 16;
static constexpr int L  = 4096;
static constexpr int NB = 4;
static constexpr int M  = NB * L;      // 16384 rows
static constexpr int NP = 3 * H * 64;  // 3072 param cols

__device__ __forceinline__ float bf2f(unsigned short u) {
    unsigned int v = ((unsigned int)u) << 16;
    return __builtin_bit_cast(float, v);
}
__device__ __forceinline__ unsigned short f2bf(float f) {
    unsigned int x = __builtin_bit_cast(unsigned int, f);
    x += 0x7fffu + ((x >> 16) & 1u);
    return (unsigned short)(x >> 16);
}
// fast sigmoid: v_exp_f32 + v_rcp_f32 (err ~1ulp each, << bf16 rounding)
__device__ __forceinline__ float fsigmoid(float v) {
    return __builtin_amdgcn_rcpf(1.0f + __expf(-v));
}
__device__ __forceinline__ void async_lds16(void* lds, const void* g) {
    __builtin_amdgcn_global_load_lds(
        (const __attribute__((address_space(1))) unsigned int*)g,
        (__attribute__((address_space(3))) unsigned int*)lds,
        16, 0, 0);
}

// ---------------- init: prefix[4] = 0 ----------------
__global__ void init_prefix_kernel(int* __restrict__ prefix) {
    if (threadIdx.x < NB) prefix[threadIdx.x] = 0;
}

// ---------------- plain fp32 -> bf16 cast ----------------
__global__ __launch_bounds__(256) void cvt_bf16_kernel(const float* __restrict__ src,
                                                       unsigned short* __restrict__ dst, int n4) {
    const int i = (blockIdx.x * 256 + threadIdx.x);
    if (i < n4) {
        const float4 v = reinterpret_cast<const float4*>(src)[i];
        ushort4 o;
        o.x = f2bf(v.x); o.y = f2bf(v.y); o.z = f2bf(v.z); o.w = f2bf(v.w);
        reinterpret_cast<ushort4*>(dst)[i] = o;
    }
}

// ---------------- gathered weight cast (one dst row per block) ----------------
template <int MODE>
__global__ __launch_bounds__(256) void gather_cvt_kernel(const float* __restrict__ gw,
                                                         const float* __restrict__ pw,
                                                         unsigned short* __restrict__ dst) {
    const int r = blockIdx.x;  // 0..2047
    const float* src;
    if (MODE == 0) {
        src = (r < 1024) ? (gw + (size_t)r * 1024)
                         : (pw + (size_t)(((r - 1024) >> 6) * 192 + ((r - 1024) & 63)) * 1024);
    } else {
        src = (r < 1024) ? (pw + (size_t)((r >> 6) * 192 + 64 + (r & 63)) * 1024)
                         : (pw + (size_t)(((r - 1024) >> 6) * 192 + 128 + ((r - 1024) & 63)) * 1024);
    }
    const int t = threadIdx.x * 4;
    const float4 v = *reinterpret_cast<const float4*>(src + t);
    ushort4 o;
    o.x = f2bf(v.x); o.y = f2bf(v.y); o.z = f2bf(v.z); o.w = f2bf(v.w);
    *reinterpret_cast<ushort4*>(dst + (size_t)r * 1024 + t) = o;
}

// ---------------- RMSNorm (fp32 in -> bf16 out) ----------------
__global__ __launch_bounds__(256) void rmsnorm_kernel(const float* __restrict__ x,
                                                      const float* __restrict__ w,
                                                      unsigned short* __restrict__ xn) {
    const int row = blockIdx.x;
    const int t = threadIdx.x;
    const float4 v = *reinterpret_cast<const float4*>(x + (size_t)row * D + t * 4);
    float s = v.x * v.x + v.y * v.y + v.z * v.z + v.w * v.w;
    #pragma unroll
    for (int o = 32; o > 0; o >>= 1) s += __shfl_down(s, o, 64);
    __shared__ float red[4];
    if ((t & 63) == 0) red[t >> 6] = s;
    __syncthreads();
    const float tot = red[0] + red[1] + red[2] + red[3];
    const float rinv = 1.0f / sqrtf(tot * (1.0f / D) + 1e-6f);
    const float4 wv = *reinterpret_cast<const float4*>(w + t * 4);
    ushort4 o;
    o.x = f2bf(wv.x * v.x * rinv);
    o.y = f2bf(wv.y * v.y * rinv);
    o.z = f2bf(wv.z * v.z * rinv);
    o.w = f2bf(wv.w * v.w * rinv);
    *reinterpret_cast<ushort4*>(xn + (size_t)row * D + t * 4) = o;
}

// ---------------- depthwise causal conv (K=4) + SiLU (bf16 -> bf16) --------
__global__ __launch_bounds__(256) void conv_silu_kernel(const unsigned short* __restrict__ xn,
                                                        const float* __restrict__ cw,
                                                        const float* __restrict__ cb,
                                                        unsigned short* __restrict__ xc) {
    const int row = blockIdx.x;          // b*L + l
    const int l = row & (L - 1);
    const int d0 = threadIdx.x * 4;
    float a[4];
    float wv[4][4];
    #pragma unroll
    for (int dd = 0; dd < 4; ++dd) {
        a[dd] = cb[d0 + dd];
        const float4 wr = *reinterpret_cast<const float4*>(cw + (size_t)(d0 + dd) * 4);
        wv[dd][0] = wr.x; wv[dd][1] = wr.y; wv[dd][2] = wr.z; wv[dd][3] = wr.w;
    }
    #pragma unroll
    for (int k = 0; k < 4; ++k) {
        if (l - 3 + k >= 0) {
            const ushort4 v = *reinterpret_cast<const ushort4*>(xn + (size_t)(row - 3 + k) * D + d0);
            a[0] += wv[0][k] * bf2f(v.x);
            a[1] += wv[1][k] * bf2f(v.y);
            a[2] += wv[2][k] * bf2f(v.z);
            a[3] += wv[3][k] * bf2f(v.w);
        }
    }
    ushort4 o;
    o.x = f2bf(a[0] * fsigmoid(a[0]));
    o.y = f2bf(a[1] * fsigmoid(a[1]));
    o.z = f2bf(a[2] * fsigmoid(a[2]));
    o.w = f2bf(a[3] * fsigmoid(a[3]));
    *reinterpret_cast<ushort4*>(xc + (size_t)row * D + d0) = o;
}

// ---------------- bf16 MFMA GEMM, barrier-free per-wave pipeline -----------
// Each wave stages ITS OWN A-half (64x32) and B-half (64x32) into a private
// LDS region and reads only what it wrote -> no s_barrier in the K-loop at
// all; correctness is per-wave counted vmcnt + lgkmcnt only.
// EPI 0 (N=2048): cols 0..1023 -> gate = sigmoid(v+gb) bf16; cols 1024.. -> delta
//                 = sigmoid(v+pb[idx]) into prm at h*192+s.
// EPI 1 (N=2048): B/C into prm (bias from pb); early-exit when row chunk >= prefix[b].
// EPI 2 (N=1024): y = v + bias + xres -> fp32
template <int EPI>
__global__ __launch_bounds__(256) void gemm_bt_kernel(
    const unsigned short* __restrict__ A,
    const unsigned short* __restrict__ W,
    const float* __restrict__ bias,
    const float* __restrict__ pb,
    const float* __restrict__ xres,
    float* __restrict__ outf,
    unsigned short* __restrict__ outh,
    unsigned short* __restrict__ prm,
    const int* __restrict__ prefix,
    const int N) {
    constexpr int K = 1024;
    constexpr int BK = 32;
    constexpr int NIT = K / BK;        // 32
    // per wave: 2 buffers x (A 64x32 + B 64x32) = 16 KB; 4 waves = 64 KB
    __shared__ alignas(16) unsigned short SW[32768];
    const int tid = threadIdx.x;
    const int wave = tid >> 6;
    const int lane = tid & 63;

    // bijective XCD-aware swizzle (grids here are all % 8 == 0)
    const int nwg = (int)gridDim.x;
    const int bid = ((int)blockIdx.x & 7) * (nwg >> 3) + ((int)blockIdx.x >> 3);

    const int nbn = N >> 7;
    const int bm = (bid / nbn) << 7;
    const int bn = (bid % nbn) << 7;

    if constexpr (EPI == 1) {
        const int b = bm >> 12;
        if ((bm & (L - 1)) >= prefix[b]) return;  // block-uniform exit
    }

    const int wr = wave >> 1, wc = wave & 1;
    const int lr = lane & 15, kg = lane >> 4;

    f32x4 zero = {0.f, 0.f, 0.f, 0.f};
    f32x4 acc[4][4];
    #pragma unroll
    for (int i = 0; i < 4; ++i)
        #pragma unroll
        for (int j = 0; j < 4; ++j) acc[i][j] = zero;

    unsigned short* wbase = SW + wave * 8192;
    // per-lane global staging pointers: groups of 4 lanes cover one row's 64B
    const unsigned short* aptr = A + (size_t)(bm + wr * 64 + (lane >> 2)) * K + (lane & 3) * 8;
    const unsigned short* bptr = W + (size_t)(bn + wc * 64 + (lane >> 2)) * K + (lane & 3) * 8;

    auto stage = [&](int buf, int k0) {
        unsigned short* a = wbase + buf * 4096;
        unsigned short* b = a + 2048;
        #pragma unroll
        for (int i = 0; i < 4; ++i) {  // 16 rows per instr, 4 instrs = 64 rows
            async_lds16(a + i * 512 + lane * 8, aptr + (size_t)(i * 16) * K + k0);
            async_lds16(b + i * 512 + lane * 8, bptr + (size_t)(i * 16) * K + k0);
        }
    };

    // prologue: both buffers in flight (16 loads)
    stage(0, 0);
    stage(1, BK);

    for (int t = 0; t < NIT; ++t) {
        // retire THIS buffer's 8 loads; keep the other buffer's 8 in flight
        if (t + 1 < NIT) asm volatile("s_waitcnt vmcnt(8)" ::: "memory");
        else             asm volatile("s_waitcnt vmcnt(0)" ::: "memory");
        const unsigned short* as = wbase + (t & 1) * 4096;
        const unsigned short* bs = as + 2048;
        short8 af[4], bfr[4];
        #pragma unroll
        for (int mi = 0; mi < 4; ++mi)
            af[mi] = *reinterpret_cast<const short8*>(&as[(mi * 16 + lr) * BK + kg * 8]);
        #pragma unroll
        for (int ni = 0; ni < 4; ++ni)
            bfr[ni] = *reinterpret_cast<const short8*>(&bs[(ni * 16 + lr) * BK + kg * 8]);
        #pragma unroll
        for (int mi = 0; mi < 4; ++mi)
            #pragma unroll
            for (int ni = 0; ni < 4; ++ni)
                acc[mi][ni] = __builtin_amdgcn_mfma_f32_16x16x32_bf16(af[mi], bfr[ni], acc[mi][ni], 0, 0, 0);
        // all ds_reads of this buffer retired before we overwrite it
        asm volatile("s_waitcnt lgkmcnt(0)" ::: "memory");
        if (t + 2 < NIT) stage(t & 1, (t + 2) * BK);
    }

    const int r0 = bm + wr * 64 + (lane >> 4) * 4;
    const int c0 = bn + wc * 64;
    #pragma unroll
    for (int mi = 0; mi < 4; ++mi) {
        #pragma unroll
        for (int ni = 0; ni < 4; ++ni) {
            const int col = c0 + ni * 16 + lr;
            #pragma unroll
            for (int j = 0; j < 4; ++j) {
                const int row = r0 + mi * 16 + j;
                float v = acc[mi][ni][j];
                if constexpr (EPI == 0) {
                    if (col < 1024) {
                        outh[(size_t)row * 1024 + col] = f2bf(fsigmoid(v + bias[col]));
                    } else {
                        const int c = col - 1024;
                        const int idx = (c >> 6) * 192 + (c & 63);
                        prm[(size_t)row * NP + idx] = f2bf(fsigmoid(v + pb[idx]));
                    }
                } else if constexpr (EPI == 1) {
                    int idx;
                    if (col < 1024) idx = (col >> 6) * 192 + 64 + (col & 63);
                    else { const int c = col - 1024; idx = (c >> 6) * 192 + 128 + (c & 63); }
                    v += pb[idx];
                    prm[(size_t)row * NP + idx] = f2bf(v);
                } else {
                    v += bias[col] + xres[(size_t)row * N + col];
                    outf[(size_t)row * N + col] = v;
                }
            }
        }
    }
}

// ---------------- prefix finder: delta cumprod saturation per batch ----------
__global__ __launch_bounds__(64) void prefix_kernel(const unsigned short* __restrict__ prm,
                                                    int* __restrict__ prefix) {
    const int bh = blockIdx.x;           // b*16 + h
    const int b = bh >> 4, h = bh & 15;
    const int s = threadIdx.x;
    const unsigned short* base = prm + (size_t)b * L * NP + h * 192 + s;
    float p = 1.0f;
    int lsat = L;
    for (int l = 0; l < L; l += 8) {
        float dv[8];
        #pragma unroll
        for (int j = 0; j < 8; ++j) dv[j] = bf2f(base[(size_t)(l + j) * NP]);
        #pragma unroll
        for (int j = 0; j < 8; ++j) p = p * dv[j];
        if (__all(p == 0.0f)) { lsat = l + 8; break; }
    }
    if (s == 0) atomicMax(prefix + b, lsat);
}

// ---------------- selective scan (bf16 params in, bf16 ssm out) -------------
__global__ __launch_bounds__(64) void scan_kernel(const unsigned short* __restrict__ prm,
                                                  const float* __restrict__ state,
                                                  unsigned short* __restrict__ ssm,
                                                  float* __restrict__ hlast,
                                                  const int* __restrict__ prefix) {
    const int bh = blockIdx.x;           // b*16 + h
    const int b = bh >> 4, h = bh & 15;
    const int s = threadIdx.x;           // 0..63
    const unsigned short* base = prm + (size_t)b * L * NP + h * 192 + s;
    unsigned short* ob = ssm + (size_t)b * L * D + h * 64 + s;
    const float h0 = state[(size_t)bh * 64 + s];
    float p = 1.0f, cu = 0.0f;
    bool live = true;
    int lend = 0;
    for (int l = 0; l < L && live; l += 8) {
        float dv[8], bv[8], cv[8];
        #pragma unroll
        for (int j = 0; j < 8; ++j) {
            const unsigned short* pp = base + (size_t)(l + j) * NP;
            dv[j] = bf2f(pp[0]);
            bv[j] = bf2f(pp[64]);
            cv[j] = bf2f(pp[128]);
        }
        #pragma unroll
        for (int j = 0; j < 8; ++j) {
            p = p * dv[j];
            const float u = bv[j] / (p + 1e-8f);
            cu += u;
            const float hh = p * (h0 + cu);
            ob[(size_t)(l + j) * D] = f2bf(cv[j] * hh);
        }
        lend = l + 8;
        if (__all(p == 0.0f)) live = false;
    }
    if (live) {
        hlast[(size_t)bh * 64 + s] = p * (h0 + cu);
    } else {
        hlast[(size_t)bh * 64 + s] = 0.0f;
        const int pf = prefix[b];
        for (int l = lend; l < pf; ++l) ob[(size_t)l * D] = 0;
    }
}

// ---------------- mix: mixed = g*ssm + (1-g)*xn -> bf16 (in place over gate) --
__global__ __launch_bounds__(256) void mix_kernel(unsigned short* __restrict__ gate,
                                                  const unsigned short* __restrict__ ssm,
                                                  const unsigned short* __restrict__ xn,
                                                  const int* __restrict__ prefix) {
    const size_t i = ((size_t)blockIdx.x * 256 + threadIdx.x) * 4;
    const int row = (int)(i >> 10);
    const int b = row >> 12;
    const int l = row & (L - 1);
    const ushort4 g4 = *reinterpret_cast<const ushort4*>(gate + i);
    const ushort4 x4 = *reinterpret_cast<const ushort4*>(xn + i);
    float sx = 0.f, sy = 0.f, sz = 0.f, sw = 0.f;
    if (l < prefix[b]) {
        const ushort4 s4 = *reinterpret_cast<const ushort4*>(ssm + i);
        sx = bf2f(s4.x); sy = bf2f(s4.y); sz = bf2f(s4.z); sw = bf2f(s4.w);
    }
    ushort4 o;
    float g;
    g = bf2f(g4.x); o.x = f2bf(g * sx + (1.0f - g) * bf2f(x4.x));
    g = bf2f(g4.y); o.y = f2bf(g * sy + (1.0f - g) * bf2f(x4.y));
    g = bf2f(g4.z); o.z = f2bf(g * sz + (1.0f - g) * bf2f(x4.z));
    g = bf2f(g4.w); o.w = f2bf(g * sw + (1.0f - g) * bf2f(x4.w));
    *reinterpret_cast<ushort4*>(gate + i) = o;
}

extern "C" void kernel_launch(void* const* d_in, const int* in_sizes, int n_in,
                              void* d_out, int out_size, void* d_ws, size_t ws_size,
                              hipStream_t stream) {
    const float* x      = (const float*)d_in[0];
    const float* state  = (const float*)d_in[1];
    const float* norm_w = (const float*)d_in[2];
    const float* conv_w = (const float*)d_in[3];
    const float* conv_b = (const float*)d_in[4];
    const float* pw     = (const float*)d_in[5];
    const float* pb     = (const float*)d_in[6];
    const float* gw     = (const float*)d_in[7];
    const float* gb     = (const float*)d_in[8];
    const float* ow     = (const float*)d_in[9];
    const float* ob     = (const float*)d_in[10];

    // ws: gate 32MB | prm 96MB | wgd 4MB (later owh) | bcwh 4MB | prefix 4KB
    constexpr size_t NEED = (136ull << 20) + 4096;
    if (ws_size < NEED) return;  // fail loudly instead of faulting

    char* ws = (char*)d_ws;
    unsigned short* gate  = (unsigned short*)(ws);                  // 32 MB (becomes mixed)
    unsigned short* mixed = gate;
    unsigned short* prm   = (unsigned short*)(ws + (32ull  << 20)); // 96 MB
    unsigned short* wgd   = (unsigned short*)(ws + (128ull << 20)); // 4 MB
    unsigned short* owh   = wgd;                                    // reuses wgd after GEMM0
    unsigned short* bcwh  = (unsigned short*)(ws + (132ull << 20)); // 4 MB
    int*            prefix = (int*)(ws + (136ull << 20));           // 16 B

    // d_out doubles as scratch until the final GEMM overwrites it with y.
    float* y = (float*)d_out;
    float* hlast = y + (size_t)M * D;
    unsigned short* xn  = (unsigned short*)d_out;                   // [0, 32MB)
    unsigned short* xc  = (unsigned short*)((char*)d_out + (32ull << 20)); // [32, 64MB)
    unsigned short* ssm = xc;  // scan overwrites xc region after B/C GEMM is done with it

    init_prefix_kernel<<<1, 64, 0, stream>>>(prefix);
    gather_cvt_kernel<0><<<2048, 256, 0, stream>>>(gw, pw, wgd);
    gather_cvt_kernel<1><<<2048, 256, 0, stream>>>(gw, pw, bcwh);

    rmsnorm_kernel<<<M, 256, 0, stream>>>(x, norm_w, xn);
    conv_silu_kernel<<<M, 256, 0, stream>>>(xn, conv_w, conv_b, xc);

    // GEMM0: gate + delta (N=2048)
    gemm_bt_kernel<0><<<(M / 128) * (2048 / 128), 256, 0, stream>>>(
        xc, wgd, gb, pb, nullptr, nullptr, gate, prm, nullptr, 2048);

    // ow cast into the now-dead wgd region
    cvt_bf16_kernel<<<1024, 256, 0, stream>>>(ow, owh, 1024 * 1024 / 4);

    prefix_kernel<<<NB * H, 64, 0, stream>>>(prm, prefix);

    // B/C GEMM, only live-prefix row blocks do work
    gemm_bt_kernel<1><<<(M / 128) * (2048 / 128), 256, 0, stream>>>(
        xc, bcwh, nullptr, pb, nullptr, nullptr, nullptr, prm, prefix, 2048);

    scan_kernel<<<NB * H, 64, 0, stream>>>(prm, state, ssm, hlast, prefix);

    mix_kernel<<<(M * D) / 1024, 256, 0, stream>>>(gate, ssm, xn, prefix);

    gemm_bt_kernel<2><<<(M / 128) * (1024 / 128), 256, 0, stream>>>(
        mixed, owh, ob, nullptr, x, y, nullptr, nullptr, nullptr, 1024);
}

// Round 7
// 338.550 us; speedup vs baseline: 1.0990x; 1.0990x over previous
//
#include <hip/hip_runtime.h>
#include <stdint.h>

typedef __attribute__((ext_vector_type(8))) short short8;
typedef __attribute__((ext_vector_type(4))) float f32x4;

static constexpr int D  = 1024;
static constexpr int H  = 16;
static constexpr int L  = 4096;
static constexpr int NB = 4;
static constexpr int M  = NB * L;      // 16384 rows
static constexpr int NP = 3 * H * 64;  // 3072 param cols

__device__ __forceinline__ float bf2f(unsigned short u) {
    unsigned int v = ((unsigned int)u) << 16;
    return __builtin_bit_cast(float, v);
}
__device__ __forceinline__ unsigned short f2bf(float f) {
    unsigned int x = __builtin_bit_cast(unsigned int, f);
    x += 0x7fffu + ((x >> 16) & 1u);
    return (unsigned short)(x >> 16);
}
__device__ __forceinline__ float fsigmoid(float v) {
    return __builtin_amdgcn_rcpf(1.0f + __expf(-v));
}
__device__ __forceinline__ void async_lds16(void* lds, const void* g) {
    __builtin_amdgcn_global_load_lds(
        (const __attribute__((address_space(1))) unsigned int*)g,
        (__attribute__((address_space(3))) unsigned int*)lds,
        16, 0, 0);
}

// ---------------- init: prefix[4] = 0 ----------------
__global__ void init_prefix_kernel(int* __restrict__ prefix) {
    if (threadIdx.x < NB) prefix[threadIdx.x] = 0;
}

// ---------------- plain fp32 -> bf16 cast ----------------
__global__ __launch_bounds__(256) void cvt_bf16_kernel(const float* __restrict__ src,
                                                       unsigned short* __restrict__ dst, int n4) {
    const int i = (blockIdx.x * 256 + threadIdx.x);
    if (i < n4) {
        const float4 v = reinterpret_cast<const float4*>(src)[i];
        ushort4 o;
        o.x = f2bf(v.x); o.y = f2bf(v.y); o.z = f2bf(v.z); o.w = f2bf(v.w);
        reinterpret_cast<ushort4*>(dst)[i] = o;
    }
}

// ---------------- gathered weight cast (one dst row per block) ----------------
template <int MODE>
__global__ __launch_bounds__(256) void gather_cvt_kernel(const float* __restrict__ gw,
                                                         const float* __restrict__ pw,
                                                         unsigned short* __restrict__ dst) {
    const int r = blockIdx.x;  // 0..2047
    const float* src;
    if (MODE == 0) {
        src = (r < 1024) ? (gw + (size_t)r * 1024)
                         : (pw + (size_t)(((r - 1024) >> 6) * 192 + ((r - 1024) & 63)) * 1024);
    } else {
        src = (r < 1024) ? (pw + (size_t)((r >> 6) * 192 + 64 + (r & 63)) * 1024)
                         : (pw + (size_t)(((r - 1024) >> 6) * 192 + 128 + ((r - 1024) & 63)) * 1024);
    }
    const int t = threadIdx.x * 4;
    const float4 v = *reinterpret_cast<const float4*>(src + t);
    ushort4 o;
    o.x = f2bf(v.x); o.y = f2bf(v.y); o.z = f2bf(v.z); o.w = f2bf(v.w);
    *reinterpret_cast<ushort4*>(dst + (size_t)r * 1024 + t) = o;
}

// ---------------- RMSNorm (fp32 in -> bf16 out) ----------------
__global__ __launch_bounds__(256) void rmsnorm_kernel(const float* __restrict__ x,
                                                      const float* __restrict__ w,
                                                      unsigned short* __restrict__ xn) {
    const int row = blockIdx.x;
    const int t = threadIdx.x;
    const float4 v = *reinterpret_cast<const float4*>(x + (size_t)row * D + t * 4);
    float s = v.x * v.x + v.y * v.y + v.z * v.z + v.w * v.w;
    #pragma unroll
    for (int o = 32; o > 0; o >>= 1) s += __shfl_down(s, o, 64);
    __shared__ float red[4];
    if ((t & 63) == 0) red[t >> 6] = s;
    __syncthreads();
    const float tot = red[0] + red[1] + red[2] + red[3];
    const float rinv = 1.0f / sqrtf(tot * (1.0f / D) + 1e-6f);
    const float4 wv = *reinterpret_cast<const float4*>(w + t * 4);
    ushort4 o;
    o.x = f2bf(wv.x * v.x * rinv);
    o.y = f2bf(wv.y * v.y * rinv);
    o.z = f2bf(wv.z * v.z * rinv);
    o.w = f2bf(wv.w * v.w * rinv);
    *reinterpret_cast<ushort4*>(xn + (size_t)row * D + t * 4) = o;
}

// ---------------- depthwise causal conv (K=4) + SiLU (bf16 -> bf16) --------
__global__ __launch_bounds__(256) void conv_silu_kernel(const unsigned short* __restrict__ xn,
                                                        const float* __restrict__ cw,
                                                        const float* __restrict__ cb,
                                                        unsigned short* __restrict__ xc) {
    const int row = blockIdx.x;          // b*L + l
    const int l = row & (L - 1);
    const int d0 = threadIdx.x * 4;
    float a[4];
    float wv[4][4];
    #pragma unroll
    for (int dd = 0; dd < 4; ++dd) {
        a[dd] = cb[d0 + dd];
        const float4 wr = *reinterpret_cast<const float4*>(cw + (size_t)(d0 + dd) * 4);
        wv[dd][0] = wr.x; wv[dd][1] = wr.y; wv[dd][2] = wr.z; wv[dd][3] = wr.w;
    }
    #pragma unroll
    for (int k = 0; k < 4; ++k) {
        if (l - 3 + k >= 0) {
            const ushort4 v = *reinterpret_cast<const ushort4*>(xn + (size_t)(row - 3 + k) * D + d0);
            a[0] += wv[0][k] * bf2f(v.x);
            a[1] += wv[1][k] * bf2f(v.y);
            a[2] += wv[2][k] * bf2f(v.z);
            a[3] += wv[3][k] * bf2f(v.w);
        }
    }
    ushort4 o;
    o.x = f2bf(a[0] * fsigmoid(a[0]));
    o.y = f2bf(a[1] * fsigmoid(a[1]));
    o.z = f2bf(a[2] * fsigmoid(a[2]));
    o.w = f2bf(a[3] * fsigmoid(a[3]));
    *reinterpret_cast<ushort4*>(xc + (size_t)row * D + d0) = o;
}

// ---------------- 256x256-tile bf16 MFMA GEMM, BK=64, swizzled LDS ----------
// 512 threads = 8 waves (2M x 4N), wave computes 128x64.
// LDS reads conflict-free via col ^= (row&7)*8 swizzle; global source is
// pre-swizzled so global_load_lds' linear dest matches (G21 both-sides rule).
// One vmcnt(8)+barrier per K-tile; stage(t+1) issued before the wait.
// EPI 0 (N=2048): cols<1024 gate=sigmoid bf16; cols>=1024 delta into prm.
// EPI 1 (N=2048): B/C into prm; early-exit past prefix[b].
// EPI 2 (N=1024): y = v + bias + xres (fp32).
template <int EPI>
__global__ __launch_bounds__(512) void gemm256_kernel(
    const unsigned short* __restrict__ A,
    const unsigned short* __restrict__ W,
    const float* __restrict__ bias,
    const float* __restrict__ pb,
    const float* __restrict__ xres,
    float* __restrict__ outf,
    unsigned short* __restrict__ outh,
    unsigned short* __restrict__ prm,
    const int* __restrict__ prefix,
    const int N) {
    constexpr int K = 1024;
    constexpr int BK = 64;
    constexpr int NT = K / BK;  // 16
    __shared__ alignas(16) unsigned short As[2][16384];  // 2 x 32 KB
    __shared__ alignas(16) unsigned short Bs[2][16384];  // 2 x 32 KB
    const int tid = threadIdx.x;
    const int wave = tid >> 6;
    const int lane = tid & 63;

    const int nwg = (int)gridDim.x;  // all grids here are % 8 == 0
    const int bid = ((int)blockIdx.x & 7) * (nwg >> 3) + ((int)blockIdx.x >> 3);
    const int nbn = N >> 8;
    const int bm = (bid / nbn) << 8;
    const int bn = (bid % nbn) << 8;

    if constexpr (EPI == 1) {
        if ((bm & (L - 1)) >= prefix[bm >> 12]) return;  // block-uniform exit
    }

    const int wr = wave >> 2, wc = wave & 3;
    const int lr = lane & 15, kg = lane >> 4;

    f32x4 acc[8][4];
    #pragma unroll
    for (int i = 0; i < 8; ++i)
        #pragma unroll
        for (int j = 0; j < 4; ++j) acc[i][j] = (f32x4){0.f, 0.f, 0.f, 0.f};

    // staging: pre-swizzled per-lane global source (row&7 == lane>>3 here)
    const int srow = lane >> 3;                 // 0..7
    const int scol = ((lane & 7) ^ srow) * 8;   // inverse-swizzled column
    const unsigned short* aP = A + (size_t)(bm + srow) * K + scol;
    const unsigned short* bP = W + (size_t)(bn + srow) * K + scol;

    auto stage = [&](int buf, int k0) {
        #pragma unroll
        for (int i = 0; i < 4; ++i) {
            const int g = i * 8 + wave;  // 8-row group 0..31
            async_lds16(&As[buf][g * 512 + lane * 8], aP + (size_t)(g * 8) * K + k0);
        }
        #pragma unroll
        for (int i = 0; i < 4; ++i) {
            const int g = i * 8 + wave;
            async_lds16(&Bs[buf][g * 512 + lane * 8], bP + (size_t)(g * 8) * K + k0);
        }
    };

    const int abase = (wr * 128 + lr) * 64;  // elem offset of lane's A row
    const int bbase = (wc * 64 + lr) * 64;
    const int sxor = (lr & 7) * 8;           // read-side swizzle

    stage(0, 0);
    int buf = 0;
    for (int t = 0; t < NT; ++t) {
        if (t + 1 < NT) {
            stage(buf ^ 1, (t + 1) * BK);                      // loads in flight under compute
            asm volatile("s_waitcnt vmcnt(8)" ::: "memory");   // retire tile-t's 8 only
        } else {
            asm volatile("s_waitcnt vmcnt(0)" ::: "memory");
        }
        __builtin_amdgcn_s_barrier();  // everyone's tile-t loads landed

        #pragma unroll
        for (int ks = 0; ks < 2; ++ks) {
            const int kc = ks * 32 + kg * 8;
            short8 af[8], bfv[4];
            #pragma unroll
            for (int mi = 0; mi < 8; ++mi)
                af[mi] = *reinterpret_cast<const short8*>(&As[buf][abase + mi * 1024 + (kc ^ sxor)]);
            #pragma unroll
            for (int ni = 0; ni < 4; ++ni)
                bfv[ni] = *reinterpret_cast<const short8*>(&Bs[buf][bbase + ni * 1024 + (kc ^ sxor)]);
            #pragma unroll
            for (int mi = 0; mi < 8; ++mi)
                #pragma unroll
                for (int ni = 0; ni < 4; ++ni)
                    acc[mi][ni] = __builtin_amdgcn_mfma_f32_16x16x32_bf16(af[mi], bfv[ni], acc[mi][ni], 0, 0, 0);
        }
        asm volatile("s_waitcnt lgkmcnt(0)" ::: "memory");  // my reads of buf done
        __builtin_amdgcn_s_barrier();                       // all reads done -> buf reusable
        buf ^= 1;
    }

    const int r0 = bm + wr * 128 + kg * 4;
    const int c0 = bn + wc * 64;
    #pragma unroll
    for (int mi = 0; mi < 8; ++mi) {
        #pragma unroll
        for (int ni = 0; ni < 4; ++ni) {
            const int col = c0 + ni * 16 + lr;
            #pragma unroll
            for (int j = 0; j < 4; ++j) {
                const int row = r0 + mi * 16 + j;
                float v = acc[mi][ni][j];
                if constexpr (EPI == 0) {
                    if (col < 1024) {
                        outh[(size_t)row * 1024 + col] = f2bf(fsigmoid(v + bias[col]));
                    } else {
                        const int c = col - 1024;
                        const int idx = (c >> 6) * 192 + (c & 63);
                        prm[(size_t)row * NP + idx] = f2bf(fsigmoid(v + pb[idx]));
                    }
                } else if constexpr (EPI == 1) {
                    int idx;
                    if (col < 1024) idx = (col >> 6) * 192 + 64 + (col & 63);
                    else { const int c = col - 1024; idx = (c >> 6) * 192 + 128 + (c & 63); }
                    v += pb[idx];
                    prm[(size_t)row * NP + idx] = f2bf(v);
                } else {
                    v += bias[col] + xres[(size_t)row * N + col];
                    outf[(size_t)row * N + col] = v;
                }
            }
        }
    }
}

// ---------------- prefix finder: delta cumprod saturation per batch ----------
__global__ __launch_bounds__(64) void prefix_kernel(const unsigned short* __restrict__ prm,
                                                    int* __restrict__ prefix) {
    const int bh = blockIdx.x;           // b*16 + h
    const int b = bh >> 4, h = bh & 15;
    const int s = threadIdx.x;
    const unsigned short* base = prm + (size_t)b * L * NP + h * 192 + s;
    float p = 1.0f;
    int lsat = L;
    for (int l = 0; l < L; l += 8) {
        float dv[8];
        #pragma unroll
        for (int j = 0; j < 8; ++j) dv[j] = bf2f(base[(size_t)(l + j) * NP]);
        #pragma unroll
        for (int j = 0; j < 8; ++j) p = p * dv[j];
        if (__all(p == 0.0f)) { lsat = l + 8; break; }
    }
    if (s == 0) atomicMax(prefix + b, lsat);
}

// ---------------- selective scan (bf16 params in, bf16 ssm out) -------------
__global__ __launch_bounds__(64) void scan_kernel(const unsigned short* __restrict__ prm,
                                                  const float* __restrict__ state,
                                                  unsigned short* __restrict__ ssm,
                                                  float* __restrict__ hlast,
                                                  const int* __restrict__ prefix) {
    const int bh = blockIdx.x;           // b*16 + h
    const int b = bh >> 4, h = bh & 15;
    const int s = threadIdx.x;           // 0..63
    const unsigned short* base = prm + (size_t)b * L * NP + h * 192 + s;
    unsigned short* ob = ssm + (size_t)b * L * D + h * 64 + s;
    const float h0 = state[(size_t)bh * 64 + s];
    float p = 1.0f, cu = 0.0f;
    bool live = true;
    int lend = 0;
    for (int l = 0; l < L && live; l += 8) {
        float dv[8], bv[8], cv[8];
        #pragma unroll
        for (int j = 0; j < 8; ++j) {
            const unsigned short* pp = base + (size_t)(l + j) * NP;
            dv[j] = bf2f(pp[0]);
            bv[j] = bf2f(pp[64]);
            cv[j] = bf2f(pp[128]);
        }
        #pragma unroll
        for (int j = 0; j < 8; ++j) {
            p = p * dv[j];
            const float u = bv[j] / (p + 1e-8f);
            cu += u;
            const float hh = p * (h0 + cu);
            ob[(size_t)(l + j) * D] = f2bf(cv[j] * hh);
        }
        lend = l + 8;
        if (__all(p == 0.0f)) live = false;
    }
    if (live) {
        hlast[(size_t)bh * 64 + s] = p * (h0 + cu);
    } else {
        hlast[(size_t)bh * 64 + s] = 0.0f;
        const int pf = prefix[b];
        for (int l = lend; l < pf; ++l) ob[(size_t)l * D] = 0;
    }
}

// ---------------- mix: mixed = g*ssm + (1-g)*xn -> bf16 (in place over gate) --
__global__ __launch_bounds__(256) void mix_kernel(unsigned short* __restrict__ gate,
                                                  const unsigned short* __restrict__ ssm,
                                                  const unsigned short* __restrict__ xn,
                                                  const int* __restrict__ prefix) {
    const size_t i = ((size_t)blockIdx.x * 256 + threadIdx.x) * 4;
    const int row = (int)(i >> 10);
    const int b = row >> 12;
    const int l = row & (L - 1);
    const ushort4 g4 = *reinterpret_cast<const ushort4*>(gate + i);
    const ushort4 x4 = *reinterpret_cast<const ushort4*>(xn + i);
    float sx = 0.f, sy = 0.f, sz = 0.f, sw = 0.f;
    if (l < prefix[b]) {
        const ushort4 s4 = *reinterpret_cast<const ushort4*>(ssm + i);
        sx = bf2f(s4.x); sy = bf2f(s4.y); sz = bf2f(s4.z); sw = bf2f(s4.w);
    }
    ushort4 o;
    float g;
    g = bf2f(g4.x); o.x = f2bf(g * sx + (1.0f - g) * bf2f(x4.x));
    g = bf2f(g4.y); o.y = f2bf(g * sy + (1.0f - g) * bf2f(x4.y));
    g = bf2f(g4.z); o.z = f2bf(g * sz + (1.0f - g) * bf2f(x4.z));
    g = bf2f(g4.w); o.w = f2bf(g * sw + (1.0f - g) * bf2f(x4.w));
    *reinterpret_cast<ushort4*>(gate + i) = o;
}

extern "C" void kernel_launch(void* const* d_in, const int* in_sizes, int n_in,
                              void* d_out, int out_size, void* d_ws, size_t ws_size,
                              hipStream_t stream) {
    const float* x      = (const float*)d_in[0];
    const float* state  = (const float*)d_in[1];
    const float* norm_w = (const float*)d_in[2];
    const float* conv_w = (const float*)d_in[3];
    const float* conv_b = (const float*)d_in[4];
    const float* pw     = (const float*)d_in[5];
    const float* pb     = (const float*)d_in[6];
    const float* gw     = (const float*)d_in[7];
    const float* gb     = (const float*)d_in[8];
    const float* ow     = (const float*)d_in[9];
    const float* ob     = (const float*)d_in[10];

    // ws: gate 32MB | prm 96MB | wgd 4MB (later owh) | bcwh 4MB | prefix 4KB
    constexpr size_t NEED = (136ull << 20) + 4096;
    if (ws_size < NEED) return;  // fail loudly instead of faulting

    char* ws = (char*)d_ws;
    unsigned short* gate  = (unsigned short*)(ws);                  // 32 MB (becomes mixed)
    unsigned short* mixed = gate;
    unsigned short* prm   = (unsigned short*)(ws + (32ull  << 20)); // 96 MB
    unsigned short* wgd   = (unsigned short*)(ws + (128ull << 20)); // 4 MB
    unsigned short* owh   = wgd;                                    // reuses wgd after GEMM0
    unsigned short* bcwh  = (unsigned short*)(ws + (132ull << 20)); // 4 MB
    int*            prefix = (int*)(ws + (136ull << 20));           // 16 B

    // d_out doubles as scratch until the final GEMM overwrites it with y.
    float* y = (float*)d_out;
    float* hlast = y + (size_t)M * D;
    unsigned short* xn  = (unsigned short*)d_out;                   // [0, 32MB)
    unsigned short* xc  = (unsigned short*)((char*)d_out + (32ull << 20)); // [32, 64MB)
    unsigned short* ssm = xc;  // scan overwrites xc region after B/C GEMM is done with it

    init_prefix_kernel<<<1, 64, 0, stream>>>(prefix);
    gather_cvt_kernel<0><<<2048, 256, 0, stream>>>(gw, pw, wgd);
    gather_cvt_kernel<1><<<2048, 256, 0, stream>>>(gw, pw, bcwh);

    rmsnorm_kernel<<<M, 256, 0, stream>>>(x, norm_w, xn);
    conv_silu_kernel<<<M, 256, 0, stream>>>(xn, conv_w, conv_b, xc);

    // GEMM0: gate + delta (N=2048), 256x256 tiles -> 64x8 = 512 blocks
    gemm256_kernel<0><<<(M / 256) * (2048 / 256), 512, 0, stream>>>(
        xc, wgd, gb, pb, nullptr, nullptr, gate, prm, nullptr, 2048);

    // ow cast into the now-dead wgd region
    cvt_bf16_kernel<<<1024, 256, 0, stream>>>(ow, owh, 1024 * 1024 / 4);

    prefix_kernel<<<NB * H, 64, 0, stream>>>(prm, prefix);

    // B/C GEMM, only live-prefix row blocks do work
    gemm256_kernel<1><<<(M / 256) * (2048 / 256), 512, 0, stream>>>(
        xc, bcwh, nullptr, pb, nullptr, nullptr, nullptr, prm, prefix, 2048);

    scan_kernel<<<NB * H, 64, 0, stream>>>(prm, state, ssm, hlast, prefix);

    mix_kernel<<<(M * D) / 1024, 256, 0, stream>>>(gate, ssm, xn, prefix);

    // out-GEMM: 64x4 = 256 blocks
    gemm256_kernel<2><<<(M / 256) * (1024 / 256), 512, 0, stream>>>(
        mixed, owh, ob, nullptr, x, y, nullptr, nullptr, nullptr, 1024);
}

// Round 8
// 332.082 us; speedup vs baseline: 1.1204x; 1.0195x over previous
//
#include <hip/hip_runtime.h>
#include <stdint.h>

typedef __attribute__((ext_vector_type(8))) short short8;
typedef __attribute__((ext_vector_type(4))) float f32x4;

static constexpr int D  = 1024;
static constexpr int H  = 16;
static constexpr int L  = 4096;
static constexpr int NB = 4;
static constexpr int M  = NB * L;      // 16384 rows
static constexpr int NP = 3 * H * 64;  // 3072 param cols

__device__ __forceinline__ float bf2f(unsigned short u) {
    unsigned int v = ((unsigned int)u) << 16;
    return __builtin_bit_cast(float, v);
}
__device__ __forceinline__ unsigned short f2bf(float f) {
    unsigned int x = __builtin_bit_cast(unsigned int, f);
    x += 0x7fffu + ((x >> 16) & 1u);
    return (unsigned short)(x >> 16);
}
__device__ __forceinline__ float fsigmoid(float v) {
    return __builtin_amdgcn_rcpf(1.0f + __expf(-v));
}
__device__ __forceinline__ void async_lds16(void* lds, const void* g) {
    __builtin_amdgcn_global_load_lds(
        (const __attribute__((address_space(1))) unsigned int*)g,
        (__attribute__((address_space(3))) unsigned int*)lds,
        16, 0, 0);
}

// ---------------- fused: prefix init + gathered weight casts ----------------
// blocks 0..2047   : wgd rows (gw rows | pw delta rows)
// blocks 2048..4095: bcwh rows (pw B rows | pw C rows)
__global__ __launch_bounds__(256) void prep_kernel(const float* __restrict__ gw,
                                                   const float* __restrict__ pw,
                                                   unsigned short* __restrict__ wgd,
                                                   unsigned short* __restrict__ bcwh,
                                                   int* __restrict__ prefix) {
    if (blockIdx.x == 0 && threadIdx.x < NB) prefix[threadIdx.x] = 0;
    const int rr = blockIdx.x;
    const float* src;
    unsigned short* dst;
    if (rr < 2048) {
        const int r = rr;
        src = (r < 1024) ? (gw + (size_t)r * 1024)
                         : (pw + (size_t)(((r - 1024) >> 6) * 192 + ((r - 1024) & 63)) * 1024);
        dst = wgd + (size_t)r * 1024;
    } else {
        const int r = rr - 2048;
        src = (r < 1024) ? (pw + (size_t)((r >> 6) * 192 + 64 + (r & 63)) * 1024)
                         : (pw + (size_t)(((r - 1024) >> 6) * 192 + 128 + ((r - 1024) & 63)) * 1024);
        dst = bcwh + (size_t)r * 1024;
    }
    const int t = threadIdx.x * 4;
    const float4 v = *reinterpret_cast<const float4*>(src + t);
    ushort4 o;
    o.x = f2bf(v.x); o.y = f2bf(v.y); o.z = f2bf(v.z); o.w = f2bf(v.w);
    *reinterpret_cast<ushort4*>(dst + t) = o;
}

// ---------------- plain fp32 -> bf16 cast ----------------
__global__ __launch_bounds__(256) void cvt_bf16_kernel(const float* __restrict__ src,
                                                       unsigned short* __restrict__ dst, int n4) {
    const int i = (blockIdx.x * 256 + threadIdx.x);
    if (i < n4) {
        const float4 v = reinterpret_cast<const float4*>(src)[i];
        ushort4 o;
        o.x = f2bf(v.x); o.y = f2bf(v.y); o.z = f2bf(v.z); o.w = f2bf(v.w);
        reinterpret_cast<ushort4*>(dst)[i] = o;
    }
}

// ---------------- RMSNorm (fp32 in -> bf16 out) ----------------
__global__ __launch_bounds__(256) void rmsnorm_kernel(const float* __restrict__ x,
                                                      const float* __restrict__ w,
                                                      unsigned short* __restrict__ xn) {
    const int row = blockIdx.x;
    const int t = threadIdx.x;
    const float4 v = *reinterpret_cast<const float4*>(x + (size_t)row * D + t * 4);
    float s = v.x * v.x + v.y * v.y + v.z * v.z + v.w * v.w;
    #pragma unroll
    for (int o = 32; o > 0; o >>= 1) s += __shfl_down(s, o, 64);
    __shared__ float red[4];
    if ((t & 63) == 0) red[t >> 6] = s;
    __syncthreads();
    const float tot = red[0] + red[1] + red[2] + red[3];
    const float rinv = 1.0f / sqrtf(tot * (1.0f / D) + 1e-6f);
    const float4 wv = *reinterpret_cast<const float4*>(w + t * 4);
    ushort4 o;
    o.x = f2bf(wv.x * v.x * rinv);
    o.y = f2bf(wv.y * v.y * rinv);
    o.z = f2bf(wv.z * v.z * rinv);
    o.w = f2bf(wv.w * v.w * rinv);
    *reinterpret_cast<ushort4*>(xn + (size_t)row * D + t * 4) = o;
}

// ---------------- depthwise causal conv (K=4) + SiLU (bf16 -> bf16) --------
__global__ __launch_bounds__(256) void conv_silu_kernel(const unsigned short* __restrict__ xn,
                                                        const float* __restrict__ cw,
                                                        const float* __restrict__ cb,
                                                        unsigned short* __restrict__ xc) {
    const int row = blockIdx.x;          // b*L + l
    const int l = row & (L - 1);
    const int d0 = threadIdx.x * 4;
    float a[4];
    float wv[4][4];
    #pragma unroll
    for (int dd = 0; dd < 4; ++dd) {
        a[dd] = cb[d0 + dd];
        const float4 wr = *reinterpret_cast<const float4*>(cw + (size_t)(d0 + dd) * 4);
        wv[dd][0] = wr.x; wv[dd][1] = wr.y; wv[dd][2] = wr.z; wv[dd][3] = wr.w;
    }
    #pragma unroll
    for (int k = 0; k < 4; ++k) {
        if (l - 3 + k >= 0) {
            const ushort4 v = *reinterpret_cast<const ushort4*>(xn + (size_t)(row - 3 + k) * D + d0);
            a[0] += wv[0][k] * bf2f(v.x);
            a[1] += wv[1][k] * bf2f(v.y);
            a[2] += wv[2][k] * bf2f(v.z);
            a[3] += wv[3][k] * bf2f(v.w);
        }
    }
    ushort4 o;
    o.x = f2bf(a[0] * fsigmoid(a[0]));
    o.y = f2bf(a[1] * fsigmoid(a[1]));
    o.z = f2bf(a[2] * fsigmoid(a[2]));
    o.w = f2bf(a[3] * fsigmoid(a[3]));
    *reinterpret_cast<ushort4*>(xc + (size_t)row * D + d0) = o;
}

// ---------------- 256x256-tile bf16 MFMA GEMM, BK=64, swizzled LDS ----------
// r7 K-loop kept verbatim (measured: 0 bank conflicts, FETCH ~= compulsory).
// New this round: setprio around MFMA clusters (T5); EPI2 epilogue reads xres
// via a 2-deep software-pipelined register prefetch (exposed-HBM-latency fix).
template <int EPI>
__global__ __launch_bounds__(512) void gemm256_kernel(
    const unsigned short* __restrict__ A,
    const unsigned short* __restrict__ W,
    const float* __restrict__ bias,
    const float* __restrict__ pb,
    const float* __restrict__ xres,
    float* __restrict__ outf,
    unsigned short* __restrict__ outh,
    unsigned short* __restrict__ prm,
    const int* __restrict__ prefix,
    const int N) {
    constexpr int K = 1024;
    constexpr int BK = 64;
    constexpr int NT = K / BK;  // 16
    __shared__ alignas(16) unsigned short As[2][16384];  // 2 x 32 KB
    __shared__ alignas(16) unsigned short Bs[2][16384];  // 2 x 32 KB
    const int tid = threadIdx.x;
    const int wave = tid >> 6;
    const int lane = tid & 63;

    const int nwg = (int)gridDim.x;  // all grids here are % 8 == 0
    const int bid = ((int)blockIdx.x & 7) * (nwg >> 3) + ((int)blockIdx.x >> 3);
    const int nbn = N >> 8;
    const int bm = (bid / nbn) << 8;
    const int bn = (bid % nbn) << 8;

    if constexpr (EPI == 1) {
        if ((bm & (L - 1)) >= prefix[bm >> 12]) return;  // block-uniform exit
    }

    const int wr = wave >> 2, wc = wave & 3;
    const int lr = lane & 15, kg = lane >> 4;

    f32x4 acc[8][4];
    #pragma unroll
    for (int i = 0; i < 8; ++i)
        #pragma unroll
        for (int j = 0; j < 4; ++j) acc[i][j] = (f32x4){0.f, 0.f, 0.f, 0.f};

    // staging: pre-swizzled per-lane global source (row&7 == lane>>3 here)
    const int srow = lane >> 3;                 // 0..7
    const int scol = ((lane & 7) ^ srow) * 8;   // inverse-swizzled column
    const unsigned short* aP = A + (size_t)(bm + srow) * K + scol;
    const unsigned short* bP = W + (size_t)(bn + srow) * K + scol;

    auto stage = [&](int buf, int k0) {
        #pragma unroll
        for (int i = 0; i < 4; ++i) {
            const int g = i * 8 + wave;  // 8-row group 0..31
            async_lds16(&As[buf][g * 512 + lane * 8], aP + (size_t)(g * 8) * K + k0);
        }
        #pragma unroll
        for (int i = 0; i < 4; ++i) {
            const int g = i * 8 + wave;
            async_lds16(&Bs[buf][g * 512 + lane * 8], bP + (size_t)(g * 8) * K + k0);
        }
    };

    const int abase = (wr * 128 + lr) * 64;  // elem offset of lane's A row
    const int bbase = (wc * 64 + lr) * 64;
    const int sxor = (lr & 7) * 8;           // read-side swizzle

    stage(0, 0);
    int buf = 0;
    for (int t = 0; t < NT; ++t) {
        if (t + 1 < NT) {
            stage(buf ^ 1, (t + 1) * BK);                      // loads in flight under compute
            asm volatile("s_waitcnt vmcnt(8)" ::: "memory");   // retire tile-t's 8 only
        } else {
            asm volatile("s_waitcnt vmcnt(0)" ::: "memory");
        }
        __builtin_amdgcn_s_barrier();  // everyone's tile-t loads landed

        #pragma unroll
        for (int ks = 0; ks < 2; ++ks) {
            const int kc = ks * 32 + kg * 8;
            short8 af[8], bfv[4];
            #pragma unroll
            for (int mi = 0; mi < 8; ++mi)
                af[mi] = *reinterpret_cast<const short8*>(&As[buf][abase + mi * 1024 + (kc ^ sxor)]);
            #pragma unroll
            for (int ni = 0; ni < 4; ++ni)
                bfv[ni] = *reinterpret_cast<const short8*>(&Bs[buf][bbase + ni * 1024 + (kc ^ sxor)]);
            __builtin_amdgcn_s_setprio(1);
            #pragma unroll
            for (int mi = 0; mi < 8; ++mi)
                #pragma unroll
                for (int ni = 0; ni < 4; ++ni)
                    acc[mi][ni] = __builtin_amdgcn_mfma_f32_16x16x32_bf16(af[mi], bfv[ni], acc[mi][ni], 0, 0, 0);
            __builtin_amdgcn_s_setprio(0);
        }
        asm volatile("s_waitcnt lgkmcnt(0)" ::: "memory");  // my reads of buf done
        __builtin_amdgcn_s_barrier();                       // all reads done -> buf reusable
        buf ^= 1;
    }

    const int r0 = bm + wr * 128 + kg * 4;
    const int c0 = bn + wc * 64;

    if constexpr (EPI == 2) {
        // 2-deep software-pipelined xres prefetch: issue mi+1's 16 loads while
        // finishing mi. Static indexing only (named cur/nxt, full unroll).
        float xcur[16], xnxt[16];
        #pragma unroll
        for (int ni = 0; ni < 4; ++ni)
            #pragma unroll
            for (int j = 0; j < 4; ++j)
                xcur[ni * 4 + j] = xres[(size_t)(r0 + j) * N + c0 + ni * 16 + lr];
        #pragma unroll
        for (int mi = 0; mi < 8; ++mi) {
            if (mi < 7) {
                #pragma unroll
                for (int ni = 0; ni < 4; ++ni)
                    #pragma unroll
                    for (int j = 0; j < 4; ++j)
                        xnxt[ni * 4 + j] = xres[(size_t)(r0 + (mi + 1) * 16 + j) * N + c0 + ni * 16 + lr];
            }
            #pragma unroll
            for (int ni = 0; ni < 4; ++ni) {
                const int col = c0 + ni * 16 + lr;
                #pragma unroll
                for (int j = 0; j < 4; ++j)
                    outf[(size_t)(r0 + mi * 16 + j) * N + col] = acc[mi][ni][j] + bias[col] + xcur[ni * 4 + j];
            }
            #pragma unroll
            for (int q = 0; q < 16; ++q) xcur[q] = xnxt[q];
        }
        return;
    }

    #pragma unroll
    for (int mi = 0; mi < 8; ++mi) {
        #pragma unroll
        for (int ni = 0; ni < 4; ++ni) {
            const int col = c0 + ni * 16 + lr;
            #pragma unroll
            for (int j = 0; j < 4; ++j) {
                const int row = r0 + mi * 16 + j;
                float v = acc[mi][ni][j];
                if constexpr (EPI == 0) {
                    if (col < 1024) {
                        outh[(size_t)row * 1024 + col] = f2bf(fsigmoid(v + bias[col]));
                    } else {
                        const int c = col - 1024;
                        const int idx = (c >> 6) * 192 + (c & 63);
                        prm[(size_t)row * NP + idx] = f2bf(fsigmoid(v + pb[idx]));
                    }
                } else if constexpr (EPI == 1) {
                    int idx;
                    if (col < 1024) idx = (col >> 6) * 192 + 64 + (col & 63);
                    else { const int c = col - 1024; idx = (c >> 6) * 192 + 128 + (c & 63); }
                    v += pb[idx];
                    prm[(size_t)row * NP + idx] = f2bf(v);
                }
            }
        }
    }
}

// ---------------- prefix finder: delta cumprod saturation per batch ----------
__global__ __launch_bounds__(64) void prefix_kernel(const unsigned short* __restrict__ prm,
                                                    int* __restrict__ prefix) {
    const int bh = blockIdx.x;           // b*16 + h
    const int b = bh >> 4, h = bh & 15;
    const int s = threadIdx.x;
    const unsigned short* base = prm + (size_t)b * L * NP + h * 192 + s;
    float p = 1.0f;
    int lsat = L;
    for (int l = 0; l < L; l += 8) {
        float dv[8];
        #pragma unroll
        for (int j = 0; j < 8; ++j) dv[j] = bf2f(base[(size_t)(l + j) * NP]);
        #pragma unroll
        for (int j = 0; j < 8; ++j) p = p * dv[j];
        if (__all(p == 0.0f)) { lsat = l + 8; break; }
    }
    if (s == 0) atomicMax(prefix + b, lsat);
}

// ---------------- selective scan (bf16 params in, bf16 ssm out) -------------
__global__ __launch_bounds__(64) void scan_kernel(const unsigned short* __restrict__ prm,
                                                  const float* __restrict__ state,
                                                  unsigned short* __restrict__ ssm,
                                                  float* __restrict__ hlast,
                                                  const int* __restrict__ prefix) {
    const int bh = blockIdx.x;           // b*16 + h
    const int b = bh >> 4, h = bh & 15;
    const int s = threadIdx.x;           // 0..63
    const unsigned short* base = prm + (size_t)b * L * NP + h * 192 + s;
    unsigned short* ob = ssm + (size_t)b * L * D + h * 64 + s;
    const float h0 = state[(size_t)bh * 64 + s];
    float p = 1.0f, cu = 0.0f;
    bool live = true;
    int lend = 0;
    for (int l = 0; l < L && live; l += 8) {
        float dv[8], bv[8], cv[8];
        #pragma unroll
        for (int j = 0; j < 8; ++j) {
            const unsigned short* pp = base + (size_t)(l + j) * NP;
            dv[j] = bf2f(pp[0]);
            bv[j] = bf2f(pp[64]);
            cv[j] = bf2f(pp[128]);
        }
        #pragma unroll
        for (int j = 0; j < 8; ++j) {
            p = p * dv[j];
            const float u = bv[j] / (p + 1e-8f);
            cu += u;
            const float hh = p * (h0 + cu);
            ob[(size_t)(l + j) * D] = f2bf(cv[j] * hh);
        }
        lend = l + 8;
        if (__all(p == 0.0f)) live = false;
    }
    if (live) {
        hlast[(size_t)bh * 64 + s] = p * (h0 + cu);
    } else {
        hlast[(size_t)bh * 64 + s] = 0.0f;
        const int pf = prefix[b];
        for (int l = lend; l < pf; ++l) ob[(size_t)l * D] = 0;
    }
}

// ---------------- mix: mixed = g*ssm + (1-g)*xn -> bf16 (in place over gate) --
__global__ __launch_bounds__(256) void mix_kernel(unsigned short* __restrict__ gate,
                                                  const unsigned short* __restrict__ ssm,
                                                  const unsigned short* __restrict__ xn,
                                                  const int* __restrict__ prefix) {
    const size_t i = ((size_t)blockIdx.x * 256 + threadIdx.x) * 4;
    const int row = (int)(i >> 10);
    const int b = row >> 12;
    const int l = row & (L - 1);
    const ushort4 g4 = *reinterpret_cast<const ushort4*>(gate + i);
    const ushort4 x4 = *reinterpret_cast<const ushort4*>(xn + i);
    float sx = 0.f, sy = 0.f, sz = 0.f, sw = 0.f;
    if (l < prefix[b]) {
        const ushort4 s4 = *reinterpret_cast<const ushort4*>(ssm + i);
        sx = bf2f(s4.x); sy = bf2f(s4.y); sz = bf2f(s4.z); sw = bf2f(s4.w);
    }
    ushort4 o;
    float g;
    g = bf2f(g4.x); o.x = f2bf(g * sx + (1.0f - g) * bf2f(x4.x));
    g = bf2f(g4.y); o.y = f2bf(g * sy + (1.0f - g) * bf2f(x4.y));
    g = bf2f(g4.z); o.z = f2bf(g * sz + (1.0f - g) * bf2f(x4.z));
    g = bf2f(g4.w); o.w = f2bf(g * sw + (1.0f - g) * bf2f(x4.w));
    *reinterpret_cast<ushort4*>(gate + i) = o;
}

extern "C" void kernel_launch(void* const* d_in, const int* in_sizes, int n_in,
                              void* d_out, int out_size, void* d_ws, size_t ws_size,
                              hipStream_t stream) {
    const float* x      = (const float*)d_in[0];
    const float* state  = (const float*)d_in[1];
    const float* norm_w = (const float*)d_in[2];
    const float* conv_w = (const float*)d_in[3];
    const float* conv_b = (const float*)d_in[4];
    const float* pw     = (const float*)d_in[5];
    const float* pb     = (const float*)d_in[6];
    const float* gw     = (const float*)d_in[7];
    const float* gb     = (const float*)d_in[8];
    const float* ow     = (const float*)d_in[9];
    const float* ob     = (const float*)d_in[10];

    // ws: gate 32MB | prm 96MB | wgd 4MB (later owh) | bcwh 4MB | prefix 4KB
    constexpr size_t NEED = (136ull << 20) + 4096;
    if (ws_size < NEED) return;  // fail loudly instead of faulting

    char* ws = (char*)d_ws;
    unsigned short* gate  = (unsigned short*)(ws);                  // 32 MB (becomes mixed)
    unsigned short* mixed = gate;
    unsigned short* prm   = (unsigned short*)(ws + (32ull  << 20)); // 96 MB
    unsigned short* wgd   = (unsigned short*)(ws + (128ull << 20)); // 4 MB
    unsigned short* owh   = wgd;                                    // reuses wgd after GEMM0
    unsigned short* bcwh  = (unsigned short*)(ws + (132ull << 20)); // 4 MB
    int*            prefix = (int*)(ws + (136ull << 20));           // 16 B

    // d_out doubles as scratch until the final GEMM overwrites it with y.
    float* y = (float*)d_out;
    float* hlast = y + (size_t)M * D;
    unsigned short* xn  = (unsigned short*)d_out;                   // [0, 32MB)
    unsigned short* xc  = (unsigned short*)((char*)d_out + (32ull << 20)); // [32, 64MB)
    unsigned short* ssm = xc;  // scan overwrites xc region after B/C GEMM is done with it

    prep_kernel<<<4096, 256, 0, stream>>>(gw, pw, wgd, bcwh, prefix);

    rmsnorm_kernel<<<M, 256, 0, stream>>>(x, norm_w, xn);
    conv_silu_kernel<<<M, 256, 0, stream>>>(xn, conv_w, conv_b, xc);

    // GEMM0: gate + delta (N=2048), 256x256 tiles -> 64x8 = 512 blocks
    gemm256_kernel<0><<<(M / 256) * (2048 / 256), 512, 0, stream>>>(
        xc, wgd, gb, pb, nullptr, nullptr, gate, prm, nullptr, 2048);

    // ow cast into the now-dead wgd region
    cvt_bf16_kernel<<<1024, 256, 0, stream>>>(ow, owh, 1024 * 1024 / 4);

    prefix_kernel<<<NB * H, 64, 0, stream>>>(prm, prefix);

    // B/C GEMM, only live-prefix row blocks do work
    gemm256_kernel<1><<<(M / 256) * (2048 / 256), 512, 0, stream>>>(
        xc, bcwh, nullptr, pb, nullptr, nullptr, nullptr, prm, prefix, 2048);

    scan_kernel<<<NB * H, 64, 0, stream>>>(prm, state, ssm, hlast, prefix);

    mix_kernel<<<(M * D) / 1024, 256, 0, stream>>>(gate, ssm, xn, prefix);

    // out-GEMM: 64x4 = 256 blocks
    gemm256_kernel<2><<<(M / 256) * (1024 / 256), 512, 0, stream>>>(
        mixed, owh, ob, nullptr, x, y, nullptr, nullptr, nullptr, 1024);
}